// Round 8
// baseline (151.740 us; speedup 1.0000x reference)
//
#include <hip/hip_runtime.h>

// B=4, T=4096, C=512, H=64.  k,q,v = x@W+b; S = k qT/sqrt(C); softmax over q; out = P v.
// R8: attn rebuilt as m97-style 2-barrier K-loop at HIGH OCCUPANCY: 256-thr blocks,
// grid 1024 (4 batch x 4 j-quarters x 64 i-tiles, i fastest for XCD L2 reuse),
// 36 KB LDS + launch_bounds(256,3) -> ~3 blocks/CU so other blocks' waves cover each
// block's vmcnt(0)+barrier drain (the stall all 1-block/CU variants R3/R4/R5/R7 shared).
// Coalesced global_load_lds staging (TA-friendly), ds_read_b128 fragments, shfl-based
// P transpose. log2(e)/sqrt(C) folded into Wk/bk -> softmax = raw exp2; no online max.

#define DM 512
#define HD 64
#define TSEQ 4096
#define KSCALE (1.4426950408889634f * 0.04419417382415922f) /* log2(e)/sqrt(512) */

typedef __attribute__((ext_vector_type(8))) __bf16 bf16x8;
typedef __attribute__((ext_vector_type(4))) __bf16 bf16x4;
typedef __attribute__((ext_vector_type(2))) __bf16 bf16x2;
typedef __attribute__((ext_vector_type(4))) float f32x4;
typedef __attribute__((ext_vector_type(16))) float f32x16;
typedef __attribute__((ext_vector_type(4))) unsigned int uint4v;

__device__ __forceinline__ float fast_exp2(float x) {
#if __has_builtin(__builtin_amdgcn_exp2f)
    return __builtin_amdgcn_exp2f(x);
#else
    return exp2f(x);
#endif
}

__device__ __forceinline__ bf16x8 ld_bf16x8(const unsigned short* p) {
    return __builtin_bit_cast(bf16x8, *(const uint4v*)p);
}
__device__ __forceinline__ f32x4 mfma16(bf16x8 a, bf16x8 b, f32x4 c) {
    return __builtin_amdgcn_mfma_f32_16x16x32_bf16(a, b, c, 0, 0, 0);
}
__device__ __forceinline__ f32x16 mfma32(bf16x8 a, bf16x8 b, f32x16 c) {
    return __builtin_amdgcn_mfma_f32_32x32x16_bf16(a, b, c, 0, 0, 0);
}

// async global->LDS, 16 B per lane. LDS dst = wave-uniform base + lane*16.
typedef const __attribute__((address_space(1))) unsigned int* gas_t;
typedef __attribute__((address_space(3))) unsigned int* las_t;
__device__ __forceinline__ void async_cp16(const void* g, void* l) {
    __builtin_amdgcn_global_load_lds((gas_t)(unsigned long long)g,
                                     (las_t)(unsigned int)(unsigned long long)l,
                                     16, 0, 0);
}

// ---------------------------------------------------------------- prep: W -> W^T bf16
__global__ __launch_bounds__(256) void prep_wt(const float* __restrict__ Wk,
                                               const float* __restrict__ Wq,
                                               const float* __restrict__ Wv,
                                               unsigned short* __restrict__ WT) {
    int e = blockIdx.x * 256 + threadIdx.x;   // grid 384 = exactly 3*512*64
    int m = e >> 15;
    int idx = e & 32767;
    int h = idx >> 9;
    int cc = idx & 511;
    const float* W = (m == 0) ? Wk : ((m == 1) ? Wq : Wv);
    float v = W[cc * HD + h];
    if (m == 0) v *= KSCALE;
    ((__bf16*)WT)[m * 32768 + h * DM + cc] = (__bf16)v;
}

// ---------------------------------------------------------------- projection
// grid 1024 (16 rows each), block 256 = 4 waves (wave wv = 16-col slice n0=wv*16).
// 16x512 fp32 x-tile (32 KB) staged in one shot; 4 blocks/CU overlap latencies.
// V written as 32-j panels VT[b][pj][h][32].
__global__ __launch_bounds__(256, 4) void proj(const float* __restrict__ x,
                                               const unsigned short* __restrict__ WT,
                                               const float* __restrict__ bk,
                                               const float* __restrict__ bq,
                                               const float* __restrict__ bv,
                                               unsigned short* __restrict__ Kw,
                                               unsigned short* __restrict__ Qw,
                                               unsigned short* __restrict__ VTw) {
    __shared__ alignas(16) float xs[8192];   // 32 KB
    const int tid = threadIdx.x;
    const int wv = tid >> 6, lane = tid & 63;
    const int c = lane & 15, quad = lane >> 4;
    const int bx = blockIdx.x;
    const int n0 = wv * 16;

#pragma unroll
    for (int r = 0; r < 8; ++r) {
        int cid = r * 256 + tid;
        int row = cid >> 7, pos = cid & 127;
        int g = (pos & ~7) | ((pos ^ row) & 7);
        async_cp16((const char*)x + (size_t)(bx * 16 + row) * 2048 + g * 16,
                   (char*)xs + r * 4096 + wv * 1024);
    }
    __builtin_amdgcn_s_waitcnt(0x0f70);   // vmcnt(0)
    __syncthreads();

    const unsigned short* wtb = WT + (n0 + c) * DM + quad * 8;
    f32x4 acc[3];
#pragma unroll
    for (int m = 0; m < 3; ++m) acc[m] = (f32x4){0.f, 0.f, 0.f, 0.f};

#pragma unroll
    for (int ks = 0; ks < 16; ++ks) {
        int p0 = ks * 8 + quad * 2;
        int sp0 = (p0 & ~7) | ((p0 ^ c) & 7);
        int sp1 = ((p0 + 1) & ~7) | (((p0 + 1) ^ c) & 7);
        f32x4 xa = *(const f32x4*)((const char*)xs + c * 2048 + sp0 * 16);
        f32x4 xb = *(const f32x4*)((const char*)xs + c * 2048 + sp1 * 16);
        bf16x8 af;
        af[0] = (__bf16)xa[0]; af[1] = (__bf16)xa[1]; af[2] = (__bf16)xa[2]; af[3] = (__bf16)xa[3];
        af[4] = (__bf16)xb[0]; af[5] = (__bf16)xb[1]; af[6] = (__bf16)xb[2]; af[7] = (__bf16)xb[3];
#pragma unroll
        for (int m = 0; m < 3; ++m) {
            bf16x8 bf = ld_bf16x8(wtb + m * 32768 + ks * 32);
            acc[m] = mfma16(af, bf, acc[m]);
        }
    }

    const int row0 = bx * 16 + quad * 4;
#pragma unroll
    for (int m = 0; m < 3; ++m) {
        const float* bp = (m == 0) ? bk : ((m == 1) ? bq : bv);
        float bias = bp[n0 + c];
        if (m == 0) bias *= KSCALE;
        if (m < 2) {
            __bf16* dst = (__bf16*)((m == 0) ? Kw : Qw);
#pragma unroll
            for (int r = 0; r < 4; ++r)
                dst[(row0 + r) * HD + n0 + c] = (__bf16)(acc[m][r] + bias);
        } else {
            bf16x4 pk;
#pragma unroll
            for (int r = 0; r < 4; ++r) pk[r] = (__bf16)(acc[m][r] + bias);
            int b = bx >> 8;
            int t16 = bx & 255;
            int pj = t16 >> 1;                      // 32-j panel
            int jsub = (t16 & 1) * 16 + quad * 4;
            *(bf16x4*)(VTw + (((size_t)(b * 128 + pj)) * 64 + n0 + c) * 32 + jsub) = pk;
        }
    }
}

// ---------------------------------------------------------------- fused attention
// grid 1024: itile = bx&63 (fastest -> 8 itiles per XCD share a Q/V quarter in L2),
// jq = (bx>>6)&3 (1024-j quarter), batch = bx>>8. block 256 = 4 waves, wave jw owns
// the 32-j slice of each 128-j step. 8 steps; m97 2-barrier staging per step.
__global__ __launch_bounds__(256, 3) void attn(const unsigned short* __restrict__ Kw,
                                               const unsigned short* __restrict__ Qw,
                                               const unsigned short* __restrict__ VTw,
                                               float* __restrict__ Op,
                                               float* __restrict__ Lp) {
    __shared__ alignas(16) char smem[36864];   // staging 32K (Q 16K | V 16K); epi 35.8K

    const int tid = threadIdx.x;
    const int wv = tid >> 6, lane = tid & 63;
    const int l5 = lane >> 5, l31 = lane & 31;
    const int jw = wv;
    const int bx = blockIdx.x;
    const int itile = bx & 63, jq = (bx >> 6) & 3, batch = bx >> 8;
    const int rowbase = batch * TSEQ + itile * 64;

    // K fragments (B-operand of S', n=i), resident in regs
    bf16x8 kf[2][4];
#pragma unroll
    for (int it = 0; it < 2; ++it) {
        const unsigned short* kp = Kw + (size_t)(rowbase + it * 32 + l31) * HD;
#pragma unroll
        for (int ks = 0; ks < 4; ++ks) kf[it][ks] = ld_bf16x8(kp + ks * 16 + l5 * 8);
    }

    // LDS fragment read offsets (bytes), step-invariant
    const int jrow = jw * 32 + l31;
    int qoff[4];
#pragma unroll
    for (int ks = 0; ks < 4; ++ks)
        qoff[ks] = jrow * 128 + (((ks * 2 + l5) ^ (jrow & 7)) * 16);
    int voff[2][2];
#pragma unroll
    for (int ht = 0; ht < 2; ++ht)
#pragma unroll
        for (int k2 = 0; k2 < 2; ++k2)
            voff[ht][k2] = jw * 4096 + (ht * 32 + l31) * 64 + (((k2 * 2 + l5) ^ (l31 & 3)) * 16);

    // staging per-lane source offsets (xor-swizzled slots; dst = base + lane*16)
    const int qlo = (lane >> 3) * 128 + (((lane & 7) ^ ((lane >> 3) & 7)) * 16);
    const int vlo = (lane >> 2) * 64 + (((lane & 3) ^ ((lane >> 2) & 3)) * 16);
    const char* qsrc = (const char*)Qw + (size_t)(batch * TSEQ + jq * 1024) * 128;
    const char* vsrc = (const char*)VTw + (size_t)(batch * 128 + jq * 32) * 4096;
    char* QL = smem;
    char* VL = smem + 16384;

    f32x16 o00, o01, o10, o11;   // o[ht][it]
#pragma unroll
    for (int r = 0; r < 16; ++r) { o00[r] = 0.f; o01[r] = 0.f; o10[r] = 0.f; o11[r] = 0.f; }
    float lac0 = 0.f, lac1 = 0.f;

    for (int jt = 0; jt < 8; ++jt) {
        if (jt) __syncthreads();                  // prev step's LDS reads done
        const char* qs = qsrc + (size_t)jt * 16384;   // 128 rows x 128 B
        const char* vs = vsrc + (size_t)jt * 16384;   // 4 panels x 4 KB
#pragma unroll
        for (int rd = 0; rd < 8; ++rd)
            async_cp16(qs + rd * 4096 + wv * 1024 + qlo, QL + rd * 4096 + wv * 1024);
#pragma unroll
        for (int rv = 0; rv < 4; ++rv)
            async_cp16(vs + rv * 4096 + wv * 1024 + vlo, VL + rv * 4096 + wv * 1024);
        __builtin_amdgcn_s_waitcnt(0x0f70);       // vmcnt(0)
        __syncthreads();

        // S' = Q x K^T   (m = wave's 32 j, n = i; 2 i-tiles)
        f32x16 s0, s1;
#pragma unroll
        for (int r = 0; r < 16; ++r) { s0[r] = 0.f; s1[r] = 0.f; }
#pragma unroll
        for (int ks = 0; ks < 4; ++ks) {
            bf16x8 qa = ld_bf16x8((const unsigned short*)(QL + qoff[ks]));
            s0 = mfma32(qa, kf[0][ks], s0);
            s1 = mfma32(qa, kf[1][ks], s1);
        }

        // exp2 + pack to bf16 pairs + denominator
        unsigned int pk0[8], pk1[8];
#pragma unroll
        for (int m = 0; m < 8; ++m) {
            float a0 = fast_exp2(s0[2 * m]), a1 = fast_exp2(s0[2 * m + 1]);
            float b0 = fast_exp2(s1[2 * m]), b1 = fast_exp2(s1[2 * m + 1]);
            lac0 += a0 + a1;
            lac1 += b0 + b1;
            bf16x2 ta; ta[0] = (__bf16)a0; ta[1] = (__bf16)a1;
            bf16x2 tb; tb[0] = (__bf16)b0; tb[1] = (__bf16)b1;
            pk0[m] = __builtin_bit_cast(unsigned int, ta);
            pk1[m] = __builtin_bit_cast(unsigned int, tb);
        }

        // PV: O[h][i] += V^T x P ; B-frag of P built by cross-half shfl regroup
#pragma unroll
        for (int k2 = 0; k2 < 2; ++k2) {
            bf16x8 pb0, pb1;
            {
                unsigned int A0 = pk0[k2 * 4 + 0], A1 = pk0[k2 * 4 + 1];
                unsigned int B0 = pk0[k2 * 4 + 2], B1 = pk0[k2 * 4 + 3];
                unsigned int t0 = l5 ? A0 : B0, t1 = l5 ? A1 : B1;
                unsigned int r0 = (unsigned int)__shfl_xor((int)t0, 32, 64);
                unsigned int r1 = (unsigned int)__shfl_xor((int)t1, 32, 64);
                uint4v u;
                u[0] = l5 ? r0 : A0; u[1] = l5 ? r1 : A1;
                u[2] = l5 ? B0 : r0; u[3] = l5 ? B1 : r1;
                pb0 = __builtin_bit_cast(bf16x8, u);
            }
            {
                unsigned int A0 = pk1[k2 * 4 + 0], A1 = pk1[k2 * 4 + 1];
                unsigned int B0 = pk1[k2 * 4 + 2], B1 = pk1[k2 * 4 + 3];
                unsigned int t0 = l5 ? A0 : B0, t1 = l5 ? A1 : B1;
                unsigned int r0 = (unsigned int)__shfl_xor((int)t0, 32, 64);
                unsigned int r1 = (unsigned int)__shfl_xor((int)t1, 32, 64);
                uint4v u;
                u[0] = l5 ? r0 : A0; u[1] = l5 ? r1 : A1;
                u[2] = l5 ? B0 : r0; u[3] = l5 ? B1 : r1;
                pb1 = __builtin_bit_cast(bf16x8, u);
            }
            bf16x8 vf0 = ld_bf16x8((const unsigned short*)(VL + voff[0][k2]));
            bf16x8 vf1 = ld_bf16x8((const unsigned short*)(VL + voff[1][k2]));
            o00 = mfma32(vf0, pb0, o00);
            o01 = mfma32(vf0, pb1, o01);
            o10 = mfma32(vf1, pb0, o10);
            o11 = mfma32(vf1, pb1, o11);
        }
    }

    // ---- epilogue: combine the 4 jw partials in LDS ----
    lac0 += __shfl_xor(lac0, 32, 64);
    lac1 += __shfl_xor(lac1, 32, 64);
    __syncthreads();
    float* OCp = (float*)smem;                 // [jw4][hr32][i68] = 34816 B
    float* ldsl = (float*)(smem + 34816);      // [jw4][i64] = 1024 B
    if (l5 == 0) {
        ldsl[jw * 64 + l31] = lac0;
        ldsl[jw * 64 + 32 + l31] = lac1;
    }

#pragma unroll
    for (int ht = 0; ht < 2; ++ht) {
        const f32x16 oa = ht ? o10 : o00;      // it0 (i 0..31)
        const f32x16 ob = ht ? o11 : o01;      // it1 (i 32..63)
#pragma unroll
        for (int r = 0; r < 16; ++r) {
            int hr = (r & 3) + 8 * (r >> 2) + 4 * l5;
            OCp[(jw * 32 + hr) * 68 + l31] = oa[r];
            OCp[(jw * 32 + hr) * 68 + 32 + l31] = ob[r];
        }
        __syncthreads();
#pragma unroll
        for (int rep = 0; rep < 8; ++rep) {
            int idx = rep * 256 + tid;         // 0..2047
            int i = idx >> 5, hr = idx & 31;
            float v = OCp[(0 * 32 + hr) * 68 + i] + OCp[(1 * 32 + hr) * 68 + i]
                    + OCp[(2 * 32 + hr) * 68 + i] + OCp[(3 * 32 + hr) * 68 + i];
            Op[(size_t)jq * 1048576 + (size_t)(rowbase + i) * HD + ht * 32 + hr] = v;
        }
        if (ht == 0) {
            if (tid < 64) {
                float L = ldsl[tid] + ldsl[64 + tid] + ldsl[128 + tid] + ldsl[192 + tid];
                Lp[jq * 16384 + rowbase + tid] = L;
            }
            __syncthreads();                   // before phase-1 OCp overwrite
        }
    }
}

// ---------------------------------------------------------------- final combine
__global__ __launch_bounds__(256) void fin(const float* __restrict__ Op,
                                           const float* __restrict__ Lp,
                                           float* __restrict__ out) {
    int idx = blockIdx.x * 256 + threadIdx.x;   // grid 1024 -> 262144 threads x 4 floats
    int e = idx * 4;
    int row = e >> 6;
    f32x4 a = *(const f32x4*)(Op + e);
    f32x4 b = *(const f32x4*)(Op + 1048576 + e);
    f32x4 c = *(const f32x4*)(Op + 2097152 + e);
    f32x4 d = *(const f32x4*)(Op + 3145728 + e);
    float L = Lp[row] + Lp[16384 + row] + Lp[32768 + row] + Lp[49152 + row];
    f32x4 r;
#pragma unroll
    for (int k = 0; k < 4; ++k) r[k] = (a[k] + b[k] + c[k] + d[k]) / L;
    *(f32x4*)(out + e) = r;
}

extern "C" void kernel_launch(void* const* d_in, const int* in_sizes, int n_in,
                              void* d_out, int out_size, void* d_ws, size_t ws_size,
                              hipStream_t stream) {
    (void)in_sizes; (void)n_in; (void)out_size; (void)ws_size;
    const float* x  = (const float*)d_in[0];
    const float* Wk = (const float*)d_in[1];
    const float* bk = (const float*)d_in[2];
    const float* Wq = (const float*)d_in[3];
    const float* bq = (const float*)d_in[4];
    const float* Wv = (const float*)d_in[5];
    const float* bv = (const float*)d_in[6];

    char* ws = (char*)d_ws;
    unsigned short* WT  = (unsigned short*)(ws);               // 192 KiB
    unsigned short* Kw  = (unsigned short*)(ws + 196608);      // 2 MiB
    unsigned short* Qw  = (unsigned short*)(ws + 2293760);     // 2 MiB
    unsigned short* VTw = (unsigned short*)(ws + 4390912);     // 2 MiB (panel layout)
    float* Opart        = (float*)(ws + 6488064);              // 16 MiB (4 x 16384 x 64 f32)
    float* Lpart        = (float*)(ws + 23265280);             // 256 KiB (4 x 16384 f32)
    float* outp = (float*)d_out;

    hipLaunchKernelGGL(prep_wt, dim3(384), dim3(256), 0, stream, Wk, Wq, Wv, WT);
    hipLaunchKernelGGL(proj, dim3(1024), dim3(256), 0, stream,
                       x, WT, bk, bq, bv, Kw, Qw, VTw);
    hipLaunchKernelGGL(attn, dim3(1024), dim3(256), 0, stream, Kw, Qw, VTw, Opart, Lpart);
    hipLaunchKernelGGL(fin, dim3(1024), dim3(256), 0, stream, Opart, Lpart, outp);
}

// Round 9
// 137.738 us; speedup vs baseline: 1.1017x; 1.1017x over previous
//
#include <hip/hip_runtime.h>

// B=4, T=4096, C=512, H=64.  k,q,v = x@W+b; S = k qT/sqrt(C); softmax over q; out = P v.
// R9: REVERT to the measured-best R4 configuration (137.3 us). Rationale: R8's +14 us
// matches its +128 MB L2 traffic + bigger partial round-trip, proving ~10 us deltas are
// visible; R3/R4/R5/R7's four independent attn pipelines all land 137-141 us => kernel
// sum (~25 us by arithmetic) is small vs the fixed harness poison-fill/restore traffic
// (268 MB fills at ~75% HBM peak dominate every profile). R4 is the best-of breed:
// attn = BI128/js2 double-buffered global_load_lds pipeline, shfl-based P transpose,
// proj = single-shot 64KB stage. log2(e)/sqrt(C) folded into Wk/bk -> softmax = exp2.

#define DM 512
#define HD 64
#define TSEQ 4096
#define KSCALE (1.4426950408889634f * 0.04419417382415922f) /* log2(e)/sqrt(512) */

typedef __attribute__((ext_vector_type(8))) __bf16 bf16x8;
typedef __attribute__((ext_vector_type(4))) __bf16 bf16x4;
typedef __attribute__((ext_vector_type(2))) __bf16 bf16x2;
typedef __attribute__((ext_vector_type(4))) float f32x4;
typedef __attribute__((ext_vector_type(16))) float f32x16;
typedef __attribute__((ext_vector_type(4))) unsigned int uint4v;

__device__ __forceinline__ float fast_exp2(float x) {
#if __has_builtin(__builtin_amdgcn_exp2f)
    return __builtin_amdgcn_exp2f(x);
#else
    return exp2f(x);
#endif
}

__device__ __forceinline__ bf16x8 ld_bf16x8(const unsigned short* p) {
    return __builtin_bit_cast(bf16x8, *(const uint4v*)p);
}
__device__ __forceinline__ f32x4 mfma16(bf16x8 a, bf16x8 b, f32x4 c) {
    return __builtin_amdgcn_mfma_f32_16x16x32_bf16(a, b, c, 0, 0, 0);
}
__device__ __forceinline__ f32x16 mfma32(bf16x8 a, bf16x8 b, f32x16 c) {
    return __builtin_amdgcn_mfma_f32_32x32x16_bf16(a, b, c, 0, 0, 0);
}

// async global->LDS, 16 B per lane. LDS dst = wave-uniform base + lane*16.
typedef const __attribute__((address_space(1))) unsigned int* gas_t;
typedef __attribute__((address_space(3))) unsigned int* las_t;
__device__ __forceinline__ void async_cp16(const void* g, void* l) {
    __builtin_amdgcn_global_load_lds((gas_t)(unsigned long long)g,
                                     (las_t)(unsigned int)(unsigned long long)l,
                                     16, 0, 0);
}

// ---------------------------------------------------------------- prep: W -> W^T bf16
__global__ __launch_bounds__(256) void prep_wt(const float* __restrict__ Wk,
                                               const float* __restrict__ Wq,
                                               const float* __restrict__ Wv,
                                               unsigned short* __restrict__ WT) {
    int e = blockIdx.x * 256 + threadIdx.x;   // grid 384 = exactly 3*512*64
    int m = e >> 15;
    int idx = e & 32767;
    int h = idx >> 9;
    int cc = idx & 511;
    const float* W = (m == 0) ? Wk : ((m == 1) ? Wq : Wv);
    float v = W[cc * HD + h];
    if (m == 0) v *= KSCALE;
    ((__bf16*)WT)[m * 32768 + h * DM + cc] = (__bf16)v;
}

// ---------------------------------------------------------------- projection
// grid 512 (32 rows each), block 512 = 8 waves: rg = wv>>2 (16 rows), ng = wv&3 (16 cols).
// Whole 32x512 fp32 x-tile (64 KB) staged in ONE shot (8 cps/lane, one vmcnt+barrier).
// V written as 32-j panels: VT[b][pj][h][jsub], pj = t/32, jsub = t%32.
__global__ __launch_bounds__(512, 4) void proj(const float* __restrict__ x,
                                               const unsigned short* __restrict__ WT,
                                               const float* __restrict__ bk,
                                               const float* __restrict__ bq,
                                               const float* __restrict__ bv,
                                               unsigned short* __restrict__ Kw,
                                               unsigned short* __restrict__ Qw,
                                               unsigned short* __restrict__ VTw) {
    __shared__ alignas(16) float xs[16384];   // 64 KB
    const int tid = threadIdx.x;
    const int wv = tid >> 6, lane = tid & 63;
    const int c = lane & 15, quad = lane >> 4;
    const int ng = wv & 3, rg = wv >> 2;
    const int bx = blockIdx.x;
    const int n0 = ng * 16;

#pragma unroll
    for (int r = 0; r < 8; ++r) {
        int cid = r * 512 + tid;
        int row = cid >> 7, pos = cid & 127;
        int g = (pos & ~7) | ((pos ^ row) & 7);
        async_cp16((const char*)x + (size_t)(bx * 32 + row) * 2048 + g * 16,
                   (char*)xs + r * 8192 + wv * 1024);
    }
    __builtin_amdgcn_s_waitcnt(0x0f70);   // vmcnt(0)
    __syncthreads();

    const int arow = rg * 16 + c;
    const unsigned short* wtb = WT + (n0 + c) * DM + quad * 8;
    f32x4 acc[3];
#pragma unroll
    for (int m = 0; m < 3; ++m) acc[m] = (f32x4){0.f, 0.f, 0.f, 0.f};

#pragma unroll
    for (int ks = 0; ks < 16; ++ks) {
        int p0 = ks * 8 + quad * 2;
        int sp0 = (p0 & ~7) | ((p0 ^ arow) & 7);
        int sp1 = ((p0 + 1) & ~7) | (((p0 + 1) ^ arow) & 7);
        f32x4 xa = *(const f32x4*)((const char*)xs + arow * 2048 + sp0 * 16);
        f32x4 xb = *(const f32x4*)((const char*)xs + arow * 2048 + sp1 * 16);
        bf16x8 af;
        af[0] = (__bf16)xa[0]; af[1] = (__bf16)xa[1]; af[2] = (__bf16)xa[2]; af[3] = (__bf16)xa[3];
        af[4] = (__bf16)xb[0]; af[5] = (__bf16)xb[1]; af[6] = (__bf16)xb[2]; af[7] = (__bf16)xb[3];
#pragma unroll
        for (int m = 0; m < 3; ++m) {
            bf16x8 bf = ld_bf16x8(wtb + m * 32768 + ks * 32);
            acc[m] = mfma16(af, bf, acc[m]);
        }
    }

    const int row0 = bx * 32 + rg * 16 + quad * 4;
#pragma unroll
    for (int m = 0; m < 3; ++m) {
        const float* bp = (m == 0) ? bk : ((m == 1) ? bq : bv);
        float bias = bp[n0 + c];
        if (m == 0) bias *= KSCALE;
        if (m < 2) {
            __bf16* dst = (__bf16*)((m == 0) ? Kw : Qw);
#pragma unroll
            for (int r = 0; r < 4; ++r)
                dst[(row0 + r) * HD + n0 + c] = (__bf16)(acc[m][r] + bias);
        } else {
            bf16x4 pk;
#pragma unroll
            for (int r = 0; r < 4; ++r) pk[r] = (__bf16)(acc[m][r] + bias);
            int b = bx >> 7;
            int pj = bx & 127;                      // 32-j panel
            int jsub = rg * 16 + quad * 4;
            *(bf16x4*)(VTw + (((size_t)(b * 128 + pj)) * 64 + n0 + c) * 32 + jsub) = pk;
        }
    }
}

// ---------------------------------------------------------------- fused attention
// grid 256: batch = bx>>6, js = (bx>>5)&1 (j half), tile = bx&31 (128 i rows).
// block 512 = 8 waves: rg = wv>>2 (64 i), jc = wv&3 (32 j of each 128-j step).
// Double-buffered Q(16K)+V(16K) staging; 16 steps of BJ=128.
// P' exits QK^T in C-layout (n=i); PV B-frag built by shfl_xor(32) regroup (no LDS).
__global__ __launch_bounds__(512, 2) void attn(const unsigned short* __restrict__ Kw,
                                               const unsigned short* __restrict__ Qw,
                                               const unsigned short* __restrict__ VTw,
                                               float* __restrict__ Op,
                                               float* __restrict__ Lp) {
    __shared__ alignas(16) char smem[65536];  // 2 x (Q 16K | V 16K); epilogue alias

    const int tid = threadIdx.x;
    const int wv = tid >> 6, lane = tid & 63;
    const int l5 = lane >> 5, l31 = lane & 31;
    const int rg = wv >> 2, jc = wv & 3;
    const int bx = blockIdx.x;
    const int batch = bx >> 6, js = (bx >> 5) & 1, tile = bx & 31;
    const int rowbase = batch * TSEQ + tile * 128;

    // K fragments (B-operand of S', n=i), resident in regs
    bf16x8 kf[2][4];
#pragma unroll
    for (int it = 0; it < 2; ++it) {
        const unsigned short* kp = Kw + (size_t)(rowbase + rg * 64 + it * 32 + l31) * HD;
#pragma unroll
        for (int ks = 0; ks < 4; ++ks) kf[it][ks] = ld_bf16x8(kp + ks * 16 + l5 * 8);
    }

    // LDS fragment read offsets (bytes), step-invariant
    const int jrow = jc * 32 + l31;
    int qoff[4];
#pragma unroll
    for (int ks = 0; ks < 4; ++ks)
        qoff[ks] = jrow * 128 + (((ks * 2 + l5) ^ (jrow & 7)) * 16);
    int voff[2][2];
#pragma unroll
    for (int ht = 0; ht < 2; ++ht)
#pragma unroll
        for (int k2 = 0; k2 < 2; ++k2) {
            int h = ht * 32 + l31;
            voff[ht][k2] = h * 256 + (((jc * 4 + k2 * 2 + l5) ^ (h & 15)) * 16);
        }

    // staging per-lane global byte offsets
    const char* qg = (const char*)(Qw + (size_t)(batch * TSEQ + js * 2048) * HD);
    const char* vg = (const char*)VTw + (size_t)(batch * 128 + js * 64) * 4096;
    const int L1 = 512 + tid;
    const int qgo0 = ((tid >> 3) * 128) + (((tid & 7) ^ ((tid >> 3) & 7)) * 16);
    const int qgo1 = ((L1 >> 3) * 128) + (((L1 & 7) ^ ((L1 >> 3) & 7)) * 16);
    // V tile of a step = 4 panels x 4 KB contiguous = rows of 64 B; swizzle low-2
    const int vgo0 = ((tid >> 2) * 64) + (((tid & 3) ^ ((tid >> 2) & 3)) * 16);
    const int vgo1 = ((L1 >> 2) * 64) + (((L1 & 3) ^ ((L1 >> 2) & 3)) * 16);

    f32x16 o00, o01, o10, o11;   // o[ht][it]
#pragma unroll
    for (int r = 0; r < 16; ++r) { o00[r] = 0.f; o01[r] = 0.f; o10[r] = 0.f; o11[r] = 0.f; }
    float lac0 = 0.f, lac1 = 0.f;

    // V LDS layout note: step tile stored as 4 consecutive 4-KB panels [pj][h][32j],
    // read offsets below match (panel jc, row h, chunk k2*2+l5 with low-2 xor by h&3)
    int voff2[2][2];
#pragma unroll
    for (int ht = 0; ht < 2; ++ht)
#pragma unroll
        for (int k2 = 0; k2 < 2; ++k2)
            voff2[ht][k2] = jc * 4096 + (ht * 32 + l31) * 64 + (((k2 * 2 + l5) ^ (l31 & 3)) * 16);
    (void)voff;

    // stage step 0 into buffer 0
    {
        char* nb = smem;
        async_cp16(qg + qgo0, nb + wv * 1024);
        async_cp16(qg + qgo1, nb + 8192 + wv * 1024);
        async_cp16(vg + vgo0, nb + 16384 + wv * 1024);
        async_cp16(vg + vgo1, nb + 16384 + 8192 + wv * 1024);
    }

    for (int jt = 0; jt < 16; ++jt) {
        __builtin_amdgcn_s_waitcnt(0x0f70);   // vmcnt(0): step-jt copies done
        __syncthreads();
        const char* cb = smem + (jt & 1) * 32768;
        if (jt < 15) {
            char* nb = smem + ((jt + 1) & 1) * 32768;
            async_cp16(qg + (jt + 1) * 16384 + qgo0, nb + wv * 1024);
            async_cp16(qg + (jt + 1) * 16384 + qgo1, nb + 8192 + wv * 1024);
            async_cp16(vg + (jt + 1) * 16384 + vgo0, nb + 16384 + wv * 1024);
            async_cp16(vg + (jt + 1) * 16384 + vgo1, nb + 16384 + 8192 + wv * 1024);
            __builtin_amdgcn_sched_barrier(0);
        }
        const unsigned short* QL = (const unsigned short*)cb;
        const char* VL = cb + 16384;

        // S' = Q x K^T   (m = j32 of jc, n = i; 2 itiles)
        f32x16 s0, s1;
#pragma unroll
        for (int r = 0; r < 16; ++r) { s0[r] = 0.f; s1[r] = 0.f; }
#pragma unroll
        for (int ks = 0; ks < 4; ++ks) {
            bf16x8 qa = ld_bf16x8((const unsigned short*)((const char*)QL + qoff[ks]));
            s0 = mfma32(qa, kf[0][ks], s0);
            s1 = mfma32(qa, kf[1][ks], s1);
        }

        // exp2 + pack to bf16 pairs + denominator
        unsigned int pk0[8], pk1[8];
#pragma unroll
        for (int m = 0; m < 8; ++m) {
            float a0 = fast_exp2(s0[2 * m]), a1 = fast_exp2(s0[2 * m + 1]);
            float b0 = fast_exp2(s1[2 * m]), b1 = fast_exp2(s1[2 * m + 1]);
            lac0 += a0 + a1;
            lac1 += b0 + b1;
            bf16x2 ta; ta[0] = (__bf16)a0; ta[1] = (__bf16)a1;
            bf16x2 tb; tb[0] = (__bf16)b0; tb[1] = (__bf16)b1;
            pk0[m] = __builtin_bit_cast(unsigned int, ta);
            pk1[m] = __builtin_bit_cast(unsigned int, tb);
        }

        // PV: O[h][i] += V^T x P ; B-frag of P built by cross-half shfl regroup
#pragma unroll
        for (int k2 = 0; k2 < 2; ++k2) {
            bf16x8 pb0, pb1;
            {
                unsigned int A0 = pk0[k2 * 4 + 0], A1 = pk0[k2 * 4 + 1];
                unsigned int B0 = pk0[k2 * 4 + 2], B1 = pk0[k2 * 4 + 3];
                unsigned int t0 = l5 ? A0 : B0, t1 = l5 ? A1 : B1;
                unsigned int r0 = (unsigned int)__shfl_xor((int)t0, 32, 64);
                unsigned int r1 = (unsigned int)__shfl_xor((int)t1, 32, 64);
                uint4v u;
                u[0] = l5 ? r0 : A0; u[1] = l5 ? r1 : A1;
                u[2] = l5 ? B0 : r0; u[3] = l5 ? B1 : r1;
                pb0 = __builtin_bit_cast(bf16x8, u);
            }
            {
                unsigned int A0 = pk1[k2 * 4 + 0], A1 = pk1[k2 * 4 + 1];
                unsigned int B0 = pk1[k2 * 4 + 2], B1 = pk1[k2 * 4 + 3];
                unsigned int t0 = l5 ? A0 : B0, t1 = l5 ? A1 : B1;
                unsigned int r0 = (unsigned int)__shfl_xor((int)t0, 32, 64);
                unsigned int r1 = (unsigned int)__shfl_xor((int)t1, 32, 64);
                uint4v u;
                u[0] = l5 ? r0 : A0; u[1] = l5 ? r1 : A1;
                u[2] = l5 ? B0 : r0; u[3] = l5 ? B1 : r1;
                pb1 = __builtin_bit_cast(bf16x8, u);
            }
            bf16x8 vf0 = ld_bf16x8((const unsigned short*)(VL + voff2[0][k2]));
            bf16x8 vf1 = ld_bf16x8((const unsigned short*)(VL + voff2[1][k2]));
            o00 = mfma32(vf0, pb0, o00);
            o01 = mfma32(vf0, pb1, o01);
            o10 = mfma32(vf1, pb0, o10);
            o11 = mfma32(vf1, pb1, o11);
        }
    }

    // ---- epilogue: combine jc partials in LDS (staging buffers are dead) ----
    lac0 += __shfl_xor(lac0, 32, 64);
    lac1 += __shfl_xor(lac1, 32, 64);
    __syncthreads();
    float* OCp = (float*)smem;                 // [jc4][h32][i68] = 34816 B
    float* ldsl = (float*)(smem + 34816);      // [jc4][i128] = 2048 B
    if (l5 == 0) {
        ldsl[jc * 128 + rg * 64 + l31] = lac0;
        ldsl[jc * 128 + rg * 64 + 32 + l31] = lac1;
    }

#pragma unroll
    for (int ph = 0; ph < 4; ++ph) {
        const int ht = ph >> 1, ih = ph & 1;
        __syncthreads();
        if (rg == ih) {
            const f32x16 oa = ht ? o10 : o00;
            const f32x16 ob = ht ? o11 : o01;
#pragma unroll
            for (int r = 0; r < 16; ++r) {
                int hr = (r & 3) + 8 * (r >> 2) + 4 * l5;
                OCp[(jc * 32 + hr) * 68 + l31] = oa[r];
                OCp[(jc * 32 + hr) * 68 + 32 + l31] = ob[r];
            }
        }
        __syncthreads();
#pragma unroll
        for (int rep = 0; rep < 4; ++rep) {
            int idx = rep * 512 + tid;
            int i = idx >> 5, hr = idx & 31;
            float v = OCp[(0 * 32 + hr) * 68 + i] + OCp[(1 * 32 + hr) * 68 + i]
                    + OCp[(2 * 32 + hr) * 68 + i] + OCp[(3 * 32 + hr) * 68 + i];
            Op[(size_t)js * 1048576 + (size_t)(rowbase + ih * 64 + i) * HD + ht * 32 + hr] = v;
        }
        if (ph == 0 && tid < 128) {
            float L = ldsl[tid] + ldsl[128 + tid] + ldsl[256 + tid] + ldsl[384 + tid];
            Lp[js * 16384 + rowbase + tid] = L;
        }
    }
}

// ---------------------------------------------------------------- final combine
__global__ __launch_bounds__(512) void fin(const float* __restrict__ Op,
                                           const float* __restrict__ Lp,
                                           float* __restrict__ out) {
    int idx = blockIdx.x * 512 + threadIdx.x;   // grid 512 -> 262144 threads x 4 floats
    int e = idx * 4;
    int row = e >> 6;
    f32x4 a = *(const f32x4*)(Op + e);
    f32x4 b = *(const f32x4*)(Op + 1048576 + e);
    float L = Lp[row] + Lp[16384 + row];
    f32x4 r;
#pragma unroll
    for (int k = 0; k < 4; ++k) r[k] = (a[k] + b[k]) / L;
    *(f32x4*)(out + e) = r;
}

extern "C" void kernel_launch(void* const* d_in, const int* in_sizes, int n_in,
                              void* d_out, int out_size, void* d_ws, size_t ws_size,
                              hipStream_t stream) {
    (void)in_sizes; (void)n_in; (void)out_size; (void)ws_size;
    const float* x  = (const float*)d_in[0];
    const float* Wk = (const float*)d_in[1];
    const float* bk = (const float*)d_in[2];
    const float* Wq = (const float*)d_in[3];
    const float* bq = (const float*)d_in[4];
    const float* Wv = (const float*)d_in[5];
    const float* bv = (const float*)d_in[6];

    char* ws = (char*)d_ws;
    unsigned short* WT  = (unsigned short*)(ws);               // 192 KiB
    unsigned short* Kw  = (unsigned short*)(ws + 196608);      // 2 MiB
    unsigned short* Qw  = (unsigned short*)(ws + 2293760);     // 2 MiB
    unsigned short* VTw = (unsigned short*)(ws + 4390912);     // 2 MiB (panel layout)
    float* Opart        = (float*)(ws + 6488064);              // 8 MiB (2 x 16384 x 64 f32)
    float* Lpart        = (float*)(ws + 14876672);             // 128 KiB (2 x 16384 f32)
    float* outp = (float*)d_out;

    hipLaunchKernelGGL(prep_wt, dim3(384), dim3(256), 0, stream, Wk, Wq, Wv, WT);
    hipLaunchKernelGGL(proj, dim3(512), dim3(512), 0, stream,
                       x, WT, bk, bq, bv, Kw, Qw, VTw);
    hipLaunchKernelGGL(attn, dim3(256), dim3(512), 0, stream, Kw, Qw, VTw, Opart, Lpart);
    hipLaunchKernelGGL(fin, dim3(512), dim3(512), 0, stream, Opart, Lpart, outp);
}